// Round 1
// baseline (166.884 us; speedup 1.0000x reference)
//
#include <hip/hip_runtime.h>

// BirthDeathIntervalLoss: 2 sets × [B=32,C=4,N=64] intervals, each gathers
// birth/death from pred[B,C,H=512,W=512], diff=(b-d)^2, weighted sum.
// Weights folded analytically (see header analysis): good: -0.0625/g,
// bad: +0.0625/(64-g), plus constant 14.0.

#define H_ 512
#define W_ 512

__global__ __launch_bounds__(256) void bd_loss_kernel(
    const float* __restrict__ pred,
    const int4* __restrict__ iv0,
    const int4* __restrict__ iv1,
    float* __restrict__ out)
{
    const int tid = blockIdx.x * blockDim.x + threadIdx.x;  // [0, 16384)
    const int s   = tid >> 13;        // set index: 8192 intervals per set
    const int idx = tid & 8191;       // (b*C + c)*N + n
    const int n   = idx & 63;
    const int bc  = idx >> 6;         // b*C + c  in [0, 128)
    const int c   = bc & 3;

    // interval = {birth_row, birth_col, death_row, death_col}, 16B aligned
    const int4 iv = (s == 0 ? iv0 : iv1)[idx];

    const float birth = pred[(bc * H_ + iv.x) * W_ + iv.y];
    const float death = pred[(bc * H_ + iv.z) * W_ + iv.w];
    const float d = birth - death;
    const float diff = d * d;

    // good-interval counts packed as nibbles: set0 {1,2,1,3}, set1 {1,0,2,1}
    const int packed = (s == 0) ? 0x3121 : 0x1201;
    const int g = (packed >> (c << 2)) & 0xF;

    // g==0 => n >= g always => bad path only (no div-by-zero)
    const float w = (n < g) ? (-0.0625f / (float)g)
                            : ( 0.0625f / (float)(64 - g));
    float v = w * diff;

    // wave-64 shuffle reduction
    #pragma unroll
    for (int off = 32; off > 0; off >>= 1)
        v += __shfl_down(v, off, 64);

    __shared__ float wave_sums[4];    // 256 threads / 64 = 4 waves
    const int lane = threadIdx.x & 63;
    const int wid  = threadIdx.x >> 6;
    if (lane == 0) wave_sums[wid] = v;
    __syncthreads();

    if (threadIdx.x == 0) {
        float t = wave_sums[0] + wave_sums[1] + wave_sums[2] + wave_sums[3];
        if (blockIdx.x == 0) t += 14.0f;   // analytic constant term
        atomicAdd(out, t);                 // device-scope by default on CDNA
    }
}

extern "C" void kernel_launch(void* const* d_in, const int* in_sizes, int n_in,
                              void* d_out, int out_size, void* d_ws, size_t ws_size,
                              hipStream_t stream) {
    const float* pred = (const float*)d_in[0];
    const int4*  iv0  = (const int4*)d_in[1];
    const int4*  iv1  = (const int4*)d_in[2];
    float* out = (float*)d_out;

    // d_out is poisoned 0xAA before every launch — zero it (async, capture-safe)
    hipMemsetAsync(out, 0, sizeof(float), stream);

    // 2 * 32 * 4 * 64 = 16384 intervals, one thread each
    bd_loss_kernel<<<64, 256, 0, stream>>>(pred, iv0, iv1, out);
}

// Round 2
// 164.344 us; speedup vs baseline: 1.0155x; 1.0155x over previous
//
#include <hip/hip_runtime.h>

// BirthDeathIntervalLoss: 2 sets × [B=32,C=4,N=64] intervals, each gathers
// birth/death from pred[B,C,H=512,W=512], diff=(b-d)^2, weighted sum.
// Weights folded analytically: good interval (n < g_c): -0.0625/g_c,
// bad: +0.0625/(64-g_c); constant term 14.0 (= 0.5*beta*B*(4+3)/C... derived
// in R0 analysis). GOOD_0={1,2,1,3} -> 0x3121, GOOD_1={1,0,2,1} -> 0x1201.
//
// Two-stage reduction, NO memset: kernel1 overwrites d_ws[0..63] with block
// partials (poison-safe: every slot written unconditionally), kernel2 (one
// wave) reduces 64 partials + 14.0 and stores d_out directly.

#define H_ 512
#define W_ 512

__global__ __launch_bounds__(256) void bd_partial_kernel(
    const float* __restrict__ pred,
    const int4* __restrict__ iv0,
    const int4* __restrict__ iv1,
    float* __restrict__ partials)
{
    const int tid = blockIdx.x * blockDim.x + threadIdx.x;  // [0, 16384)
    const int s   = tid >> 13;        // set index: 8192 intervals per set
    const int idx = tid & 8191;       // (b*C + c)*N + n
    const int n   = idx & 63;
    const int bc  = idx >> 6;         // b*C + c  in [0, 128)
    const int c   = bc & 3;

    // interval = {birth_row, birth_col, death_row, death_col}, 16B aligned
    const int4 iv = (s == 0 ? iv0 : iv1)[idx];

    const float birth = pred[(bc * H_ + iv.x) * W_ + iv.y];
    const float death = pred[(bc * H_ + iv.z) * W_ + iv.w];
    const float d = birth - death;
    const float diff = d * d;

    // good-interval counts packed as nibbles: set0 {1,2,1,3}, set1 {1,0,2,1}
    const int packed = (s == 0) ? 0x3121 : 0x1201;
    const int g = (packed >> (c << 2)) & 0xF;

    // g==0 => n >= g always => bad path only (no div-by-zero)
    const float w = (n < g) ? (-0.0625f / (float)g)
                            : ( 0.0625f / (float)(64 - g));
    float v = w * diff;

    // wave-64 shuffle reduction
    #pragma unroll
    for (int off = 32; off > 0; off >>= 1)
        v += __shfl_down(v, off, 64);

    __shared__ float wave_sums[4];    // 256 threads / 64 = 4 waves
    const int lane = threadIdx.x & 63;
    const int wid  = threadIdx.x >> 6;
    if (lane == 0) wave_sums[wid] = v;
    __syncthreads();

    if (threadIdx.x == 0) {
        partials[blockIdx.x] =
            wave_sums[0] + wave_sums[1] + wave_sums[2] + wave_sums[3];
    }
}

__global__ __launch_bounds__(64) void bd_final_kernel(
    const float* __restrict__ partials,
    float* __restrict__ out)
{
    float v = partials[threadIdx.x];   // exactly 64 partials, one per lane
    #pragma unroll
    for (int off = 32; off > 0; off >>= 1)
        v += __shfl_down(v, off, 64);
    if (threadIdx.x == 0) out[0] = v + 14.0f;  // analytic constant term
}

extern "C" void kernel_launch(void* const* d_in, const int* in_sizes, int n_in,
                              void* d_out, int out_size, void* d_ws, size_t ws_size,
                              hipStream_t stream) {
    const float* pred = (const float*)d_in[0];
    const int4*  iv0  = (const int4*)d_in[1];
    const int4*  iv1  = (const int4*)d_in[2];
    float* partials = (float*)d_ws;   // 64 floats, all overwritten each call
    float* out = (float*)d_out;

    // 2 * 32 * 4 * 64 = 16384 intervals, one thread each
    bd_partial_kernel<<<64, 256, 0, stream>>>(pred, iv0, iv1, partials);
    bd_final_kernel<<<1, 64, 0, stream>>>(partials, out);
}